// Round 1
// baseline (106.096 us; speedup 1.0000x reference)
//
#include <hip/hip_runtime.h>

// LightPrompt inner_structure_update (dense form), MI355X gfx950.
// Outputs (f32, concatenated): x[4096,128] | adj[4096,4096] | edge_attr[4096,4096,4]
// Write-bound: 337.6 MB of output per call. dot = tok@tok.T via f32 vector FMA
// (no fp32-input MFMA on CDNA4), fused epilogue.

static constexpr int Tn = 4096;
static constexpr int Dm = 128;
static constexpr int En = 4;
static constexpr float THRE = 0.55f;
static constexpr float SLOPE = 0.01f;

#define LDA 132  // 128 + 4 pad: breaks power-of-2 LDS bank stride, keeps 16B row alignment

__global__ __launch_bounds__(256, 2) void lp_fused(const float* __restrict__ tokens,
                                                   const float* __restrict__ edge_token,
                                                   float* __restrict__ out) {
    __shared__ float As[64][LDA];
    __shared__ float Bs[64][LDA];

    const int i0 = blockIdx.y << 6;
    const int j0 = blockIdx.x << 6;
    const int tid = threadIdx.x;

    // Stage 64 A-rows and 64 B-rows (each 128 f32) into LDS, float4-coalesced.
    {
        const int c4 = (tid & 31) << 2;  // float column 0..124 step 4
        const int r8 = tid >> 5;         // 0..7
#pragma unroll
        for (int p = 0; p < 8; ++p) {
            const int row = (p << 3) + r8;
            const float4 av = *reinterpret_cast<const float4*>(tokens + (size_t)(i0 + row) * Dm + c4);
            *reinterpret_cast<float4*>(&As[row][c4]) = av;
            const float4 bv = *reinterpret_cast<const float4*>(tokens + (size_t)(j0 + row) * Dm + c4);
            *reinterpret_cast<float4*>(&Bs[row][c4]) = bv;
        }
    }
    __syncthreads();

    // Thread tile: rows i0 + ty*4 + r (r=0..3), cols j0 + tx + 16*c (c=0..3).
    // Strided cols keep Bs ds_read_b128 at a free 2-way bank conflict.
    const int tx = tid & 15;
    const int ty = tid >> 4;

    float acc[4][4];
#pragma unroll
    for (int r = 0; r < 4; ++r)
#pragma unroll
        for (int c = 0; c < 4; ++c) acc[r][c] = 0.0f;

#pragma unroll 4
    for (int k = 0; k < Dm; k += 4) {
        float4 a4[4], b4[4];
#pragma unroll
        for (int r = 0; r < 4; ++r)
            a4[r] = *reinterpret_cast<const float4*>(&As[(ty << 2) + r][k]);
#pragma unroll
        for (int c = 0; c < 4; ++c)
            b4[c] = *reinterpret_cast<const float4*>(&Bs[tx + (c << 4)][k]);
#pragma unroll
        for (int r = 0; r < 4; ++r)
#pragma unroll
            for (int c = 0; c < 4; ++c)
                acc[r][c] = fmaf(a4[r].x, b4[c].x,
                            fmaf(a4[r].y, b4[c].y,
                            fmaf(a4[r].z, b4[c].z,
                            fmaf(a4[r].w, b4[c].w, acc[r][c]))));
    }

    const float e0 = edge_token[0];
    const float e1 = edge_token[1];
    const float e2 = edge_token[2];
    const float e3 = edge_token[3];

    float* __restrict__ adj  = out + (size_t)Tn * Dm;       // after x
    float* __restrict__ attr = adj + (size_t)Tn * Tn;       // after adj

#pragma unroll
    for (int r = 0; r < 4; ++r) {
        const int i = i0 + (ty << 2) + r;
#pragma unroll
        for (int c = 0; c < 4; ++c) {
            const int j = j0 + tx + (c << 4);
            const float d = acc[r][c];
            const float sim = 1.0f / (1.0f + __expf(-d));
            const float m = (sim >= THRE) ? 1.0f : 0.0f;
            adj[(size_t)i * Tn + j] = sim * m;   // where(sim<thre, 0, sim)
            float4 at;
            float v;
            v = d * e0; at.x = (v > 0.0f ? v : SLOPE * v) * m;
            v = d * e1; at.y = (v > 0.0f ? v : SLOPE * v) * m;
            v = d * e2; at.z = (v > 0.0f ? v : SLOPE * v) * m;
            v = d * e3; at.w = (v > 0.0f ? v : SLOPE * v) * m;
            *reinterpret_cast<float4*>(attr + ((size_t)i * Tn + j) * En) = at;
        }
    }
}

// x output = tokens verbatim (524288 floats = 131072 float4).
__global__ __launch_bounds__(256) void copy_x4(const float* __restrict__ in,
                                               float* __restrict__ out) {
    const int idx = blockIdx.x * blockDim.x + threadIdx.x;
    reinterpret_cast<float4*>(out)[idx] = reinterpret_cast<const float4*>(in)[idx];
}

extern "C" void kernel_launch(void* const* d_in, const int* in_sizes, int n_in,
                              void* d_out, int out_size, void* d_ws, size_t ws_size,
                              hipStream_t stream) {
    const float* tokens     = (const float*)d_in[0];  // [1,4096,128] f32
    const float* edge_token = (const float*)d_in[1];  // [1,4] f32
    float* out = (float*)d_out;

    hipLaunchKernelGGL(copy_x4, dim3((Tn * Dm / 4) / 256), dim3(256), 0, stream, tokens, out);
    hipLaunchKernelGGL(lp_fused, dim3(Tn / 64, Tn / 64), dim3(256), 0, stream,
                       tokens, edge_token, out);
}

// Round 3
// 97.632 us; speedup vs baseline: 1.0867x; 1.0867x over previous
//
#include <hip/hip_runtime.h>

// LightPrompt inner_structure_update (dense form), MI355X gfx950.
// Outputs (f32, concat): x[4096,128] | adj[4096,4096] | edge_attr[4096,4096,4]
// Write-bound: 337.6 MB output/call. dot = tok@tok.T via f32 vector FMA
// (no fp32-input MFMA on CDNA4; bf16 MFMA rejected: mask-flip risk at the
// sigmoid threshold on near-boundary diagonal elements).
//
// R3 = R2 with the nontemporal float4 fixed (native ext_vector_type, the
// builtin rejects HIP_vector_type). R2 changes vs R1 (106 us):
//  - split-K LDS staging (two 64-wide k passes): LDS 67.6KB -> 34.8KB,
//    occupancy 2 -> 4 blocks/CU (16 waves/CU) so store-drain overlaps compute
//  - nontemporal stores for adj/attr (pure streaming writes)
//  - x-copy folded into main kernel (one launch total)

typedef float f32x4 __attribute__((ext_vector_type(4)));

static constexpr int Tn = 4096;
static constexpr int Dm = 128;
static constexpr int En = 4;
static constexpr float THRE = 0.55f;
static constexpr float SLOPE = 0.01f;

#define LDK 68  // 64 + 4 pad: row byte stride 272 (16B-aligned), banks spread 4/row

__global__ __launch_bounds__(256, 4) void lp_fused(const float* __restrict__ tokens,
                                                   const float* __restrict__ edge_token,
                                                   float* __restrict__ out) {
    __shared__ float As[64][LDK];
    __shared__ float Bs[64][LDK];

    const int tid = threadIdx.x;
    const int i0 = blockIdx.y << 6;
    const int j0 = blockIdx.x << 6;

    // x output = tokens verbatim (131072 float4) handled by first 512 blocks.
    const int bid = blockIdx.y * (Tn / 64) + blockIdx.x;
    if (bid < 512) {
        reinterpret_cast<f32x4*>(out)[bid * 256 + tid] =
            reinterpret_cast<const f32x4*>(tokens)[bid * 256 + tid];
    }

    const int tx = tid & 15;
    const int ty = tid >> 4;

    float acc[4][4];
#pragma unroll
    for (int r = 0; r < 4; ++r)
#pragma unroll
        for (int c = 0; c < 4; ++c) acc[r][c] = 0.0f;

#pragma unroll
    for (int kp = 0; kp < 2; ++kp) {
        const int kbase = kp << 6;
        // Stage 64 rows x 64 floats of A and B. 1024 float4 per array,
        // 4 per thread. 16-lane groups read/write 64B contiguous.
        {
            const int c4 = (tid & 15) << 2;  // float col 0..60 step 4
            const int r16 = tid >> 4;        // 0..15
#pragma unroll
            for (int p = 0; p < 4; ++p) {
                const int row = (p << 4) + r16;
                *reinterpret_cast<f32x4*>(&As[row][c4]) =
                    *reinterpret_cast<const f32x4*>(tokens + (size_t)(i0 + row) * Dm + kbase + c4);
                *reinterpret_cast<f32x4*>(&Bs[row][c4]) =
                    *reinterpret_cast<const f32x4*>(tokens + (size_t)(j0 + row) * Dm + kbase + c4);
            }
        }
        __syncthreads();

        // Rows i0 + ty*4 + r, cols j0 + tx + 16*c.
        // Bs read: 16 lanes hit rows 0..15 -> 2-way bank alias (free).
        // As read: 16 lanes same address -> broadcast.
#pragma unroll 4
        for (int k = 0; k < 64; k += 4) {
            f32x4 a4[4], b4[4];
#pragma unroll
            for (int r = 0; r < 4; ++r)
                a4[r] = *reinterpret_cast<const f32x4*>(&As[(ty << 2) + r][k]);
#pragma unroll
            for (int c = 0; c < 4; ++c)
                b4[c] = *reinterpret_cast<const f32x4*>(&Bs[tx + (c << 4)][k]);
#pragma unroll
            for (int r = 0; r < 4; ++r)
#pragma unroll
                for (int c = 0; c < 4; ++c)
                    acc[r][c] = fmaf(a4[r].x, b4[c].x,
                                fmaf(a4[r].y, b4[c].y,
                                fmaf(a4[r].z, b4[c].z,
                                fmaf(a4[r].w, b4[c].w, acc[r][c]))));
        }
        __syncthreads();
    }

    const float e0 = edge_token[0];
    const float e1 = edge_token[1];
    const float e2 = edge_token[2];
    const float e3 = edge_token[3];

    float* __restrict__ adj  = out + (size_t)Tn * Dm;
    float* __restrict__ attr = adj + (size_t)Tn * Tn;

#pragma unroll
    for (int r = 0; r < 4; ++r) {
        const int i = i0 + (ty << 2) + r;
#pragma unroll
        for (int c = 0; c < 4; ++c) {
            const int j = j0 + tx + (c << 4);
            const float d = acc[r][c];
            const float sim = 1.0f / (1.0f + __expf(-d));
            const float m = (sim >= THRE) ? 1.0f : 0.0f;
            __builtin_nontemporal_store(sim * m, adj + (size_t)i * Tn + j);
            f32x4 at;
            float v;
            v = d * e0; at.x = (v > 0.0f ? v : SLOPE * v) * m;
            v = d * e1; at.y = (v > 0.0f ? v : SLOPE * v) * m;
            v = d * e2; at.z = (v > 0.0f ? v : SLOPE * v) * m;
            v = d * e3; at.w = (v > 0.0f ? v : SLOPE * v) * m;
            __builtin_nontemporal_store(at, reinterpret_cast<f32x4*>(attr + ((size_t)i * Tn + j) * En));
        }
    }
}

extern "C" void kernel_launch(void* const* d_in, const int* in_sizes, int n_in,
                              void* d_out, int out_size, void* d_ws, size_t ws_size,
                              hipStream_t stream) {
    const float* tokens     = (const float*)d_in[0];  // [1,4096,128] f32
    const float* edge_token = (const float*)d_in[1];  // [1,4] f32
    float* out = (float*)d_out;

    hipLaunchKernelGGL(lp_fused, dim3(Tn / 64, Tn / 64), dim3(256), 0, stream,
                       tokens, edge_token, out);
}